// Round 2
// baseline (1472.098 us; speedup 1.0000x reference)
//
#include <hip/hip_runtime.h>

#define TINV 0.125f  // 1/TEMPERATURE
constexpr int S = 1024;
constexpr int D = 64;

typedef float vf4 __attribute__((ext_vector_type(4)));

// ---------------- Kernel A: logits1 = (q/T) @ k^T  (written to attn region) ----
// grid (8 j-tiles, 8 i-tiles, 16 bh), block 256   [unchanged — near roofline model]
__global__ __launch_bounds__(256) void k_attn1(const float* __restrict__ q,
                                               const float* __restrict__ k,
                                               float* __restrict__ attn) {
  __shared__ float Qs[128][36];
  __shared__ float Ks[128][36];
  const int z  = blockIdx.z;          // b*8+h
  const int i0 = blockIdx.y * 128;
  const int j0 = blockIdx.x * 128;
  const int t  = threadIdx.x;
  const int tx = t & 15;
  const int ty = t >> 4;

  const float4* qsrc = (const float4*)(q + ((size_t)z * S + i0) * D);
  const float4* ksrc = (const float4*)(k + ((size_t)z * S + j0) * D);

  float acc[8][8];
#pragma unroll
  for (int r = 0; r < 8; ++r)
#pragma unroll
    for (int c = 0; c < 8; ++c) acc[r][c] = 0.f;

#pragma unroll
  for (int p = 0; p < 2; ++p) {
    if (p) __syncthreads();
#pragma unroll
    for (int it = 0; it < 4; ++it) {
      int fidx = t + it * 256;
      int row  = fidx >> 3;
      int c8   = fidx & 7;
      float4 qv = qsrc[row * 16 + p * 8 + c8];
      qv.x *= TINV; qv.y *= TINV; qv.z *= TINV; qv.w *= TINV;
      *(float4*)&Qs[row][c8 * 4] = qv;
      *(float4*)&Ks[row][c8 * 4] = ksrc[row * 16 + p * 8 + c8];
    }
    __syncthreads();
#pragma unroll
    for (int dc = 0; dc < 8; ++dc) {
      float4 kf[8];
#pragma unroll
      for (int c = 0; c < 8; ++c) kf[c] = *(const float4*)&Ks[tx + 16 * c][dc * 4];
#pragma unroll
      for (int r = 0; r < 8; ++r) {
        const float4 qf = *(const float4*)&Qs[ty + 16 * r][dc * 4];
#pragma unroll
        for (int c = 0; c < 8; ++c) {
          acc[r][c] += qf.x * kf[c].x + qf.y * kf[c].y + qf.z * kf[c].z + qf.w * kf[c].w;
        }
      }
    }
  }

  float* dst = attn + ((size_t)z * S + i0) * S + j0;
#pragma unroll
  for (int r = 0; r < 8; ++r)
#pragma unroll
    for (int c = 0; c < 8; ++c)
      dst[(size_t)(ty + 16 * r) * S + tx + 16 * c] = acc[r][c];
}

// ---------------- Kernel B: += (q/T)@rpr^T, mask, softmax (in-place on attn) --
// grid (1024 i, 2 b), block 256.
// logits kept entirely in registers (the old 32 KB LDS array was a
// same-thread same-index round trip — pure overhead + occupancy cap);
// all stream-once loads (rpr, attn1, mask) are non-temporal so they don't
// evict the attn stores we want L2-resident for k_pv.
__global__ __launch_bounds__(256) void k_attn2_softmax(const float* __restrict__ q,
                                                       const float* __restrict__ rpr,
                                                       const int* __restrict__ mask,
                                                       float* __restrict__ attn) {
  __shared__ float qsh[8][64];
  __shared__ float redA[4][8];
  __shared__ float redB[4][8];

  const int i    = blockIdx.x;
  const int b    = blockIdx.y;
  const int t    = threadIdx.x;
  const int lane = t & 63;
  const int wid  = t >> 6;

  // stage q[b,:,i,:]/T  (8 heads x 64) into LDS
  if (t < 128) {
    int h  = t >> 4;
    int c4 = t & 15;
    const float4* src = (const float4*)(q + (((size_t)b * 8 + h) * S + i) * D);
    float4 v = src[c4];
    v.x *= TINV; v.y *= TINV; v.z *= TINV; v.w *= TINV;
    *(float4*)&qsh[h][c4 * 4] = v;
  }
  __syncthreads();

  const vf4*   rsrc   = (const vf4*)(rpr + ((size_t)b * S + i) * (size_t)S * D);
  const float* a1base = attn + ((size_t)b * 8 * S + i) * S;  // + h*S*S + j
  const int*   mrow   = mask + ((size_t)b * S + i) * S;

  // phase 1: stream rpr rows (NT), accumulate all 8 heads, fold attn1 + mask
  // into REGISTERS lg[8][4].  jt loop fully unrolled so lg indexing is static.
  float lg[8][4];
#pragma unroll
  for (int jt = 0; jt < 4; ++jt) {
    const int j = t + jt * 256;
    const vf4* rrow = rsrc + (size_t)j * 16;
    float acc_h[8];
#pragma unroll
    for (int h = 0; h < 8; ++h) acc_h[h] = 0.f;
#pragma unroll
    for (int half = 0; half < 2; ++half) {
      vf4 rv[8];
#pragma unroll
      for (int u = 0; u < 8; ++u)
        rv[u] = __builtin_nontemporal_load(rrow + half * 8 + u);  // 8 outstanding b128
#pragma unroll
      for (int u = 0; u < 8; ++u) {
        const int dc = half * 8 + u;
#pragma unroll
        for (int h = 0; h < 8; ++h) {
          const vf4 qv = *(const vf4*)&qsh[h][dc * 4];  // wave-broadcast read
          acc_h[h] += rv[u].x * qv.x + rv[u].y * qv.y + rv[u].z * qv.z + rv[u].w * qv.w;
        }
      }
    }
    const int m = __builtin_nontemporal_load(mrow + j);
#pragma unroll
    for (int h = 0; h < 8; ++h) {
      float a1  = __builtin_nontemporal_load(a1base + (size_t)h * S * S + j);
      float val = acc_h[h] + a1;
      lg[h][jt] = (m == 0) ? -1e9f : val;
    }
  }

  // phase 2: softmax per head row (lg already lives in registers)
  float rmax[8];
#pragma unroll
  for (int h = 0; h < 8; ++h) {
    float m = fmaxf(fmaxf(lg[h][0], lg[h][1]), fmaxf(lg[h][2], lg[h][3]));
#pragma unroll
    for (int off = 32; off >= 1; off >>= 1) m = fmaxf(m, __shfl_xor(m, off));
    if (lane == 0) redA[wid][h] = m;
  }
  __syncthreads();
#pragma unroll
  for (int h = 0; h < 8; ++h)
    rmax[h] = fmaxf(fmaxf(redA[0][h], redA[1][h]), fmaxf(redA[2][h], redA[3][h]));

  float rsum[8];
#pragma unroll
  for (int h = 0; h < 8; ++h) {
#pragma unroll
    for (int jt = 0; jt < 4; ++jt) lg[h][jt] = __expf(lg[h][jt] - rmax[h]);
    float s = lg[h][0] + lg[h][1] + lg[h][2] + lg[h][3];
#pragma unroll
    for (int off = 32; off >= 1; off >>= 1) s += __shfl_xor(s, off);
    if (lane == 0) redB[wid][h] = s;
  }
  __syncthreads();
#pragma unroll
  for (int h = 0; h < 8; ++h)
    rsum[h] = redB[0][h] + redB[1][h] + redB[2][h] + redB[3][h];

  float* adst = attn + ((size_t)b * 8 * S + i) * S;
#pragma unroll
  for (int h = 0; h < 8; ++h) {
    const float inv = 1.0f / rsum[h];
#pragma unroll
    for (int jt = 0; jt < 4; ++jt)
      adst[(size_t)h * S * S + t + jt * 256] = lg[h][jt] * inv;  // cached store: k_pv re-reads
  }
}

// ---------------- Kernel C: output = attn @ v --------------------------------
// 32-row i-tiles -> 512 blocks (2 blocks/CU instead of 1 — latency hiding);
// XCD-chunked block swizzle so each XCD's L2 serves only 2 bh's v (512 KB,
// L2-resident); attn read is non-temporal (stream-once, 64 MB) so it cannot
// evict v.
// grid (32 i-tiles, 16 bh), block 256
__global__ __launch_bounds__(256) void k_pv(const float* __restrict__ attn,
                                            const float* __restrict__ v,
                                            float* __restrict__ out) {
  __shared__ float Ps[32][68];
  __shared__ float Vs[64][68];
  // bijective XCD-chunked swizzle: 512 blocks, 8 XCDs, 64 blocks/XCD chunk.
  const int wg  = blockIdx.x + (int)gridDim.x * blockIdx.y;  // 0..511
  const int swz = (wg & 7) * 64 + (wg >> 3);
  const int bh  = swz >> 5;         // 0..15  (2 consecutive bh per XCD)
  const int i0  = (swz & 31) * 32;  // 32 i-tiles of 32 rows
  const int t   = threadIdx.x;
  const int tx  = t & 15;
  const int ty  = t >> 4;

  float acc[2][4];
#pragma unroll
  for (int r = 0; r < 2; ++r)
#pragma unroll
    for (int c = 0; c < 4; ++c) acc[r][c] = 0.f;

  const float* abase = attn + ((size_t)bh * S + i0) * S;
  const vf4*   vbase = (const vf4*)(v + (size_t)bh * S * D);

  for (int jt = 0; jt < 16; ++jt) {
    if (jt) __syncthreads();
    const int j0 = jt * 64;
    // stage P tile: 32 rows x 16 float4 = 512 slots (2 iters), NT loads
#pragma unroll
    for (int it = 0; it < 2; ++it) {
      int fidx = t + it * 256;
      int row  = fidx >> 4;
      int c4   = fidx & 15;
      *(vf4*)&Ps[row][c4 * 4] =
          __builtin_nontemporal_load((const vf4*)(abase + (size_t)row * S + j0 + c4 * 4));
    }
    // stage V tile: 64 rows x 16 float4 = 1024 slots (4 iters), cached (reused)
#pragma unroll
    for (int it = 0; it < 4; ++it) {
      int fidx = t + it * 256;
      int row  = fidx >> 4;
      int c4   = fidx & 15;
      *(vf4*)&Vs[row][c4 * 4] = vbase[(size_t)(j0 + row) * 16 + c4];
    }
    __syncthreads();
#pragma unroll
    for (int jc = 0; jc < 16; ++jc) {
      float vr[4][4];
#pragma unroll
      for (int jj = 0; jj < 4; ++jj) {
        vf4 tv = *(const vf4*)&Vs[jc * 4 + jj][tx * 4];
        vr[jj][0] = tv.x; vr[jj][1] = tv.y; vr[jj][2] = tv.z; vr[jj][3] = tv.w;
      }
#pragma unroll
      for (int r = 0; r < 2; ++r) {
        vf4 pf = *(const vf4*)&Ps[ty + 16 * r][jc * 4];
        float pa[4] = {pf.x, pf.y, pf.z, pf.w};
#pragma unroll
        for (int c = 0; c < 4; ++c) {
#pragma unroll
          for (int jj = 0; jj < 4; ++jj) acc[r][c] += pa[jj] * vr[jj][c];
        }
      }
    }
  }

  float* obase = out + (size_t)bh * S * D;
#pragma unroll
  for (int r = 0; r < 2; ++r) {
    vf4 st = {acc[r][0], acc[r][1], acc[r][2], acc[r][3]};
    *(vf4*)(obase + (size_t)(i0 + ty + 16 * r) * D + tx * 4) = st;
  }
}

extern "C" void kernel_launch(void* const* d_in, const int* in_sizes, int n_in,
                              void* d_out, int out_size, void* d_ws, size_t ws_size,
                              hipStream_t stream) {
  const float* q    = (const float*)d_in[0];
  const float* k    = (const float*)d_in[1];
  const float* v    = (const float*)d_in[2];
  const int*   mask = (const int*)d_in[3];
  const float* rpr  = (const float*)d_in[4];

  float* out  = (float*)d_out;                    // (2,8,1024,64)
  float* attn = out + (size_t)2 * 8 * S * D;      // (2,8,1024,1024), also logits scratch

  hipLaunchKernelGGL(k_attn1,         dim3(8, 8, 16), dim3(256), 0, stream, q, k, attn);
  hipLaunchKernelGGL(k_attn2_softmax, dim3(1024, 2),  dim3(256), 0, stream, q, rpr, mask, attn);
  hipLaunchKernelGGL(k_pv,            dim3(32, 16),   dim3(256), 0, stream, attn, v, out);
}

// Round 3
// 1102.485 us; speedup vs baseline: 1.3353x; 1.3353x over previous
//
#include <hip/hip_runtime.h>

#define TINV 0.125f  // 1/TEMPERATURE
constexpr int S = 1024;
constexpr int D = 64;

typedef float vf4 __attribute__((ext_vector_type(4)));

// ---------------- Kernel A: logits1 = (q/T) @ k^T  (written to attn region) ----
// grid (8 j-tiles, 8 i-tiles, 16 bh), block 256
__global__ __launch_bounds__(256) void k_attn1(const float* __restrict__ q,
                                               const float* __restrict__ k,
                                               float* __restrict__ attn) {
  __shared__ float Qs[128][36];
  __shared__ float Ks[128][36];
  const int z  = blockIdx.z;          // b*8+h
  const int i0 = blockIdx.y * 128;
  const int j0 = blockIdx.x * 128;
  const int t  = threadIdx.x;
  const int tx = t & 15;
  const int ty = t >> 4;

  const float4* qsrc = (const float4*)(q + ((size_t)z * S + i0) * D);
  const float4* ksrc = (const float4*)(k + ((size_t)z * S + j0) * D);

  float acc[8][8];
#pragma unroll
  for (int r = 0; r < 8; ++r)
#pragma unroll
    for (int c = 0; c < 8; ++c) acc[r][c] = 0.f;

#pragma unroll
  for (int p = 0; p < 2; ++p) {
    if (p) __syncthreads();
#pragma unroll
    for (int it = 0; it < 4; ++it) {
      int fidx = t + it * 256;
      int row  = fidx >> 3;
      int c8   = fidx & 7;
      float4 qv = qsrc[row * 16 + p * 8 + c8];
      qv.x *= TINV; qv.y *= TINV; qv.z *= TINV; qv.w *= TINV;
      *(float4*)&Qs[row][c8 * 4] = qv;
      *(float4*)&Ks[row][c8 * 4] = ksrc[row * 16 + p * 8 + c8];
    }
    __syncthreads();
#pragma unroll
    for (int dc = 0; dc < 8; ++dc) {
      float4 kf[8];
#pragma unroll
      for (int c = 0; c < 8; ++c) kf[c] = *(const float4*)&Ks[tx + 16 * c][dc * 4];
#pragma unroll
      for (int r = 0; r < 8; ++r) {
        const float4 qf = *(const float4*)&Qs[ty + 16 * r][dc * 4];
#pragma unroll
        for (int c = 0; c < 8; ++c) {
          acc[r][c] += qf.x * kf[c].x + qf.y * kf[c].y + qf.z * kf[c].z + qf.w * kf[c].w;
        }
      }
    }
  }

  float* dst = attn + ((size_t)z * S + i0) * S + j0;
#pragma unroll
  for (int r = 0; r < 8; ++r)
#pragma unroll
    for (int c = 0; c < 8; ++c)
      dst[(size_t)(ty + 16 * r) * S + tx + 16 * c] = acc[r][c];
}

// ---------------- Kernel B: += (q/T)@rpr^T, mask, softmax (in-place on attn) --
// grid (1024 i, 2 b), block 256.
// REVERT: logits back in LDS (register version hit VGPR=256 + ~1.5 GB scratch
// spill traffic — WRITE_SIZE 9x ideal).  LDS round-trip keeps VGPR <= 128 and
// 4 blocks/CU.
// NEW: two j-columns per thread in phase 1 — halves the broadcast qsh
// ds_read_b128 count (512 -> 256 per thread), the dominant LDS-pipe cost.
// rpr loads stay non-temporal (536 MB stream-once; keeps attn L3-resident).
__global__ __launch_bounds__(256) void k_attn2_softmax(const float* __restrict__ q,
                                                       const float* __restrict__ rpr,
                                                       const int* __restrict__ mask,
                                                       float* __restrict__ attn) {
  __shared__ float qsh[8][64];
  __shared__ float logits[8][1024];
  __shared__ float redA[4][8];
  __shared__ float redB[4][8];

  const int i    = blockIdx.x;
  const int b    = blockIdx.y;
  const int t    = threadIdx.x;
  const int lane = t & 63;
  const int wid  = t >> 6;

  // stage q[b,:,i,:]/T  (8 heads x 64) into LDS
  if (t < 128) {
    int h  = t >> 4;
    int c4 = t & 15;
    const float4* src = (const float4*)(q + (((size_t)b * 8 + h) * S + i) * D);
    float4 v = src[c4];
    v.x *= TINV; v.y *= TINV; v.z *= TINV; v.w *= TINV;
    *(float4*)&qsh[h][c4 * 4] = v;
  }
  __syncthreads();

  const vf4*   rsrc   = (const vf4*)(rpr + ((size_t)b * S + i) * (size_t)S * D);
  const float* a1base = attn + ((size_t)b * 8 * S + i) * S;  // + h*S*S + j
  const int*   mrow   = mask + ((size_t)b * S + i) * S;

  // phase 1: stream rpr rows (NT), two j-columns per thread, accumulate all
  // 8 heads, fold attn1 + mask -> LDS logits.
#pragma unroll
  for (int jp = 0; jp < 2; ++jp) {
    const int ja = t + (2 * jp) * 256;
    const int jb = ja + 256;
    const vf4* ra = rsrc + (size_t)ja * 16;
    const vf4* rb = rsrc + (size_t)jb * 16;
    float accA[8], accB[8];
#pragma unroll
    for (int h = 0; h < 8; ++h) { accA[h] = 0.f; accB[h] = 0.f; }
#pragma unroll
    for (int half = 0; half < 2; ++half) {
      vf4 rva[8], rvb[8];
#pragma unroll
      for (int u = 0; u < 8; ++u) {
        rva[u] = __builtin_nontemporal_load(ra + half * 8 + u);
        rvb[u] = __builtin_nontemporal_load(rb + half * 8 + u);
      }
#pragma unroll
      for (int u = 0; u < 8; ++u) {
        const int dc = half * 8 + u;
#pragma unroll
        for (int h = 0; h < 8; ++h) {
          const vf4 qv = *(const vf4*)&qsh[h][dc * 4];  // one broadcast read, two dots
          accA[h] += rva[u].x * qv.x + rva[u].y * qv.y + rva[u].z * qv.z + rva[u].w * qv.w;
          accB[h] += rvb[u].x * qv.x + rvb[u].y * qv.y + rvb[u].z * qv.z + rvb[u].w * qv.w;
        }
      }
    }
    const int ma = mrow[ja];
    const int mb = mrow[jb];
#pragma unroll
    for (int h = 0; h < 8; ++h) {
      float va = accA[h] + a1base[(size_t)h * S * S + ja];
      float vb = accB[h] + a1base[(size_t)h * S * S + jb];
      logits[h][ja] = (ma == 0) ? -1e9f : va;
      logits[h][jb] = (mb == 0) ? -1e9f : vb;
    }
  }

  // phase 2: softmax per head row (own LDS writes are same-thread ordered)
  float lg[8][4];
#pragma unroll
  for (int h = 0; h < 8; ++h)
#pragma unroll
    for (int jt = 0; jt < 4; ++jt) lg[h][jt] = logits[h][t + jt * 256];

  float rmax[8];
#pragma unroll
  for (int h = 0; h < 8; ++h) {
    float m = fmaxf(fmaxf(lg[h][0], lg[h][1]), fmaxf(lg[h][2], lg[h][3]));
#pragma unroll
    for (int off = 32; off >= 1; off >>= 1) m = fmaxf(m, __shfl_xor(m, off));
    if (lane == 0) redA[wid][h] = m;
  }
  __syncthreads();
#pragma unroll
  for (int h = 0; h < 8; ++h)
    rmax[h] = fmaxf(fmaxf(redA[0][h], redA[1][h]), fmaxf(redA[2][h], redA[3][h]));

  float rsum[8];
#pragma unroll
  for (int h = 0; h < 8; ++h) {
#pragma unroll
    for (int jt = 0; jt < 4; ++jt) lg[h][jt] = __expf(lg[h][jt] - rmax[h]);
    float s = lg[h][0] + lg[h][1] + lg[h][2] + lg[h][3];
#pragma unroll
    for (int off = 32; off >= 1; off >>= 1) s += __shfl_xor(s, off);
    if (lane == 0) redB[wid][h] = s;
  }
  __syncthreads();
#pragma unroll
  for (int h = 0; h < 8; ++h)
    rsum[h] = redB[0][h] + redB[1][h] + redB[2][h] + redB[3][h];

  float* adst = attn + ((size_t)b * 8 * S + i) * S;
#pragma unroll
  for (int h = 0; h < 8; ++h) {
    const float inv = 1.0f / rsum[h];
#pragma unroll
    for (int jt = 0; jt < 4; ++jt)
      adst[(size_t)h * S * S + t + jt * 256] = lg[h][jt] * inv;  // cached: k_pv re-reads
  }
}

// ---------------- Kernel C: output = attn @ v --------------------------------
// 32-row i-tiles -> 512 blocks (2 blocks/CU — latency hiding); XCD-chunked
// swizzle so each XCD's L2 serves only 2 bh's v; attn read non-temporal.
// grid (32 i-tiles, 16 bh), block 256
__global__ __launch_bounds__(256) void k_pv(const float* __restrict__ attn,
                                            const float* __restrict__ v,
                                            float* __restrict__ out) {
  __shared__ float Ps[32][68];
  __shared__ float Vs[64][68];
  const int wg  = blockIdx.x + (int)gridDim.x * blockIdx.y;  // 0..511
  const int swz = (wg & 7) * 64 + (wg >> 3);
  const int bh  = swz >> 5;         // 0..15  (2 consecutive bh per XCD)
  const int i0  = (swz & 31) * 32;  // 32 i-tiles of 32 rows
  const int t   = threadIdx.x;
  const int tx  = t & 15;
  const int ty  = t >> 4;

  float acc[2][4];
#pragma unroll
  for (int r = 0; r < 2; ++r)
#pragma unroll
    for (int c = 0; c < 4; ++c) acc[r][c] = 0.f;

  const float* abase = attn + ((size_t)bh * S + i0) * S;
  const vf4*   vbase = (const vf4*)(v + (size_t)bh * S * D);

  for (int jt = 0; jt < 16; ++jt) {
    if (jt) __syncthreads();
    const int j0 = jt * 64;
#pragma unroll
    for (int it = 0; it < 2; ++it) {
      int fidx = t + it * 256;
      int row  = fidx >> 4;
      int c4   = fidx & 15;
      *(vf4*)&Ps[row][c4 * 4] =
          __builtin_nontemporal_load((const vf4*)(abase + (size_t)row * S + j0 + c4 * 4));
    }
#pragma unroll
    for (int it = 0; it < 4; ++it) {
      int fidx = t + it * 256;
      int row  = fidx >> 4;
      int c4   = fidx & 15;
      *(vf4*)&Vs[row][c4 * 4] = vbase[(size_t)(j0 + row) * 16 + c4];
    }
    __syncthreads();
#pragma unroll
    for (int jc = 0; jc < 16; ++jc) {
      float vr[4][4];
#pragma unroll
      for (int jj = 0; jj < 4; ++jj) {
        vf4 tv = *(const vf4*)&Vs[jc * 4 + jj][tx * 4];
        vr[jj][0] = tv.x; vr[jj][1] = tv.y; vr[jj][2] = tv.z; vr[jj][3] = tv.w;
      }
#pragma unroll
      for (int r = 0; r < 2; ++r) {
        vf4 pf = *(const vf4*)&Ps[ty + 16 * r][jc * 4];
        float pa[4] = {pf.x, pf.y, pf.z, pf.w};
#pragma unroll
        for (int c = 0; c < 4; ++c) {
#pragma unroll
          for (int jj = 0; jj < 4; ++jj) acc[r][c] += pa[jj] * vr[jj][c];
        }
      }
    }
  }

  float* obase = out + (size_t)bh * S * D;
#pragma unroll
  for (int r = 0; r < 2; ++r) {
    vf4 st = {acc[r][0], acc[r][1], acc[r][2], acc[r][3]};
    *(vf4*)(obase + (size_t)(i0 + ty + 16 * r) * D + tx * 4) = st;
  }
}

extern "C" void kernel_launch(void* const* d_in, const int* in_sizes, int n_in,
                              void* d_out, int out_size, void* d_ws, size_t ws_size,
                              hipStream_t stream) {
  const float* q    = (const float*)d_in[0];
  const float* k    = (const float*)d_in[1];
  const float* v    = (const float*)d_in[2];
  const int*   mask = (const int*)d_in[3];
  const float* rpr  = (const float*)d_in[4];

  float* out  = (float*)d_out;                    // (2,8,1024,64)
  float* attn = out + (size_t)2 * 8 * S * D;      // (2,8,1024,1024), also logits scratch

  hipLaunchKernelGGL(k_attn1,         dim3(8, 8, 16), dim3(256), 0, stream, q, k, attn);
  hipLaunchKernelGGL(k_attn2_softmax, dim3(1024, 2),  dim3(256), 0, stream, q, rpr, mask, attn);
  hipLaunchKernelGGL(k_pv,            dim3(32, 16),   dim3(256), 0, stream, attn, v, out);
}

// Round 4
// 889.299 us; speedup vs baseline: 1.6553x; 1.2397x over previous
//
#include <hip/hip_runtime.h>

#define TINV 0.125f  // 1/TEMPERATURE
constexpr int S = 1024;
constexpr int D = 64;

typedef float vf4 __attribute__((ext_vector_type(4)));

// ---------------- Kernel A: logits1 = (q/T) @ k^T  (written to attn region) ----
// grid (8 j-tiles, 8 i-tiles, 16 bh), block 256
__global__ __launch_bounds__(256) void k_attn1(const float* __restrict__ q,
                                               const float* __restrict__ k,
                                               float* __restrict__ attn) {
  __shared__ float Qs[128][36];
  __shared__ float Ks[128][36];
  const int z  = blockIdx.z;          // b*8+h
  const int i0 = blockIdx.y * 128;
  const int j0 = blockIdx.x * 128;
  const int t  = threadIdx.x;
  const int tx = t & 15;
  const int ty = t >> 4;

  const float4* qsrc = (const float4*)(q + ((size_t)z * S + i0) * D);
  const float4* ksrc = (const float4*)(k + ((size_t)z * S + j0) * D);

  float acc[8][8];
#pragma unroll
  for (int r = 0; r < 8; ++r)
#pragma unroll
    for (int c = 0; c < 8; ++c) acc[r][c] = 0.f;

#pragma unroll
  for (int p = 0; p < 2; ++p) {
    if (p) __syncthreads();
#pragma unroll
    for (int it = 0; it < 4; ++it) {
      int fidx = t + it * 256;
      int row  = fidx >> 3;
      int c8   = fidx & 7;
      float4 qv = qsrc[row * 16 + p * 8 + c8];
      qv.x *= TINV; qv.y *= TINV; qv.z *= TINV; qv.w *= TINV;
      *(float4*)&Qs[row][c8 * 4] = qv;
      *(float4*)&Ks[row][c8 * 4] = ksrc[row * 16 + p * 8 + c8];
    }
    __syncthreads();
#pragma unroll
    for (int dc = 0; dc < 8; ++dc) {
      float4 kf[8];
#pragma unroll
      for (int c = 0; c < 8; ++c) kf[c] = *(const float4*)&Ks[tx + 16 * c][dc * 4];
#pragma unroll
      for (int r = 0; r < 8; ++r) {
        const float4 qf = *(const float4*)&Qs[ty + 16 * r][dc * 4];
#pragma unroll
        for (int c = 0; c < 8; ++c) {
          acc[r][c] += qf.x * kf[c].x + qf.y * kf[c].y + qf.z * kf[c].z + qf.w * kf[c].w;
        }
      }
    }
  }

  float* dst = attn + ((size_t)z * S + i0) * S + j0;
#pragma unroll
  for (int r = 0; r < 8; ++r)
#pragma unroll
    for (int c = 0; c < 8; ++c)
      dst[(size_t)(ty + 16 * r) * S + tx + 16 * c] = acc[r][c];
}

// ---------------- Kernel B: += (q/T)@rpr^T, mask, softmax (in-place on attn) --
// grid (1024 i, 2 b), block 256.
// rpr staged in 64-row LDS tiles with fully-coalesced global reads, XOR-16
// slot swizzle for conflict-free row reads, next-tile loads issued before
// current tile's compute (latency hidden).  Thread = (row t&63, 2 heads).
__global__ __launch_bounds__(256) void k_attn2_softmax(const float* __restrict__ q,
                                                       const float* __restrict__ rpr,
                                                       const int* __restrict__ mask,
                                                       float* __restrict__ attn) {
  __shared__ float qsh[8][64];
  __shared__ float Rs[64][64];       // rpr tile, slots XOR-swizzled within rows
  __shared__ float logits[8][1024];
  __shared__ float redA[4][8];
  __shared__ float redB[4][8];

  const int i    = blockIdx.x;
  const int b    = blockIdx.y;
  const int t    = threadIdx.x;
  const int lane = t & 63;
  const int wid  = t >> 6;

  if (t < 128) {
    int h  = t >> 4;
    int c4 = t & 15;
    const float4* src = (const float4*)(q + (((size_t)b * 8 + h) * S + i) * D);
    float4 v = src[c4];
    v.x *= TINV; v.y *= TINV; v.z *= TINV; v.w *= TINV;
    *(float4*)&qsh[h][c4 * 4] = v;
  }
  __syncthreads();

  const vf4*   rsrc   = (const vf4*)(rpr + ((size_t)b * S + i) * (size_t)S * D);
  const float* a1base = attn + ((size_t)b * 8 * S + i) * S;  // + h*S*S + j
  const int*   mrow   = mask + ((size_t)b * S + i) * S;

  const int r       = t & 63;        // row this thread computes
  const int h0      = (t >> 6) * 2;  // head pair
  const int st_row0 = t >> 4;        // staging row base (0..15)
  const int st_sp   = t & 15;        // physical slot this thread writes
  const int st_sl   = st_sp ^ st_row0;  // logical slot (row&15 == st_row0 for all it)

  vf4 ld[4];
#pragma unroll
  for (int it = 0; it < 4; ++it)
    ld[it] = __builtin_nontemporal_load(rsrc + (size_t)(st_row0 + it * 16) * 16 + st_sl);

  for (int jt = 0; jt < 16; ++jt) {
    if (jt) __syncthreads();               // all reads of previous tile done
#pragma unroll
    for (int it = 0; it < 4; ++it)
      *(vf4*)&Rs[st_row0 + it * 16][st_sp * 4] = ld[it];
    __syncthreads();                       // Rs ready

    if (jt < 15) {
      const int j0n = (jt + 1) * 64;
#pragma unroll
      for (int it = 0; it < 4; ++it)
        ld[it] = __builtin_nontemporal_load(rsrc + (size_t)(j0n + st_row0 + it * 16) * 16 + st_sl);
    }

    const int j = jt * 64 + r;
    const float a1_0 = a1base[(size_t)h0 * S * S + j];
    const float a1_1 = a1base[(size_t)(h0 + 1) * S * S + j];
    const int   m    = mrow[j];

    float acc0 = 0.f, acc1 = 0.f;
#pragma unroll
    for (int half = 0; half < 2; ++half) {
      vf4 rd[8];
#pragma unroll
      for (int u = 0; u < 8; ++u)
        rd[u] = *(const vf4*)&Rs[r][(((half * 8 + u) ^ (r & 15)) * 4)];
#pragma unroll
      for (int u = 0; u < 8; ++u) {
        const int dc = half * 8 + u;
        const vf4 q0 = *(const vf4*)&qsh[h0][dc * 4];        // wave-uniform broadcast
        const vf4 q1 = *(const vf4*)&qsh[h0 + 1][dc * 4];
        acc0 += rd[u].x * q0.x + rd[u].y * q0.y + rd[u].z * q0.z + rd[u].w * q0.w;
        acc1 += rd[u].x * q1.x + rd[u].y * q1.y + rd[u].z * q1.z + rd[u].w * q1.w;
      }
    }
    logits[h0][j]     = (m == 0) ? -1e9f : (acc0 + a1_0);
    logits[h0 + 1][j] = (m == 0) ? -1e9f : (acc1 + a1_1);
  }
  __syncthreads();   // logits written by other threads

  float lg[8][4];
#pragma unroll
  for (int h = 0; h < 8; ++h)
#pragma unroll
    for (int jt = 0; jt < 4; ++jt) lg[h][jt] = logits[h][t + jt * 256];

  float rmax[8];
#pragma unroll
  for (int h = 0; h < 8; ++h) {
    float m = fmaxf(fmaxf(lg[h][0], lg[h][1]), fmaxf(lg[h][2], lg[h][3]));
#pragma unroll
    for (int off = 32; off >= 1; off >>= 1) m = fmaxf(m, __shfl_xor(m, off));
    if (lane == 0) redA[wid][h] = m;
  }
  __syncthreads();
#pragma unroll
  for (int h = 0; h < 8; ++h)
    rmax[h] = fmaxf(fmaxf(redA[0][h], redA[1][h]), fmaxf(redA[2][h], redA[3][h]));

  float rsum[8];
#pragma unroll
  for (int h = 0; h < 8; ++h) {
#pragma unroll
    for (int jt = 0; jt < 4; ++jt) lg[h][jt] = __expf(lg[h][jt] - rmax[h]);
    float s = lg[h][0] + lg[h][1] + lg[h][2] + lg[h][3];
#pragma unroll
    for (int off = 32; off >= 1; off >>= 1) s += __shfl_xor(s, off);
    if (lane == 0) redB[wid][h] = s;
  }
  __syncthreads();
#pragma unroll
  for (int h = 0; h < 8; ++h)
    rsum[h] = redB[0][h] + redB[1][h] + redB[2][h] + redB[3][h];

  float* adst = attn + ((size_t)b * 8 * S + i) * S;
#pragma unroll
  for (int h = 0; h < 8; ++h) {
    const float inv = 1.0f / rsum[h];
#pragma unroll
    for (int jt = 0; jt < 4; ++jt)
      adst[(size_t)h * S * S + t + jt * 256] = lg[h][jt] * inv;  // cached: k_pv re-reads
  }
}

// ---------------- Kernel C: output = attn @ v --------------------------------
// grid (32 i-tiles, 16 bh), block 256
__global__ __launch_bounds__(256) void k_pv(const float* __restrict__ attn,
                                            const float* __restrict__ v,
                                            float* __restrict__ out) {
  __shared__ float Ps[32][68];
  __shared__ float Vs[64][68];
  const int wg  = blockIdx.x + (int)gridDim.x * blockIdx.y;  // 0..511
  const int swz = (wg & 7) * 64 + (wg >> 3);
  const int bh  = swz >> 5;         // 0..15  (2 consecutive bh per XCD)
  const int i0  = (swz & 31) * 32;  // 32 i-tiles of 32 rows
  const int t   = threadIdx.x;
  const int tx  = t & 15;
  const int ty  = t >> 4;

  float acc[2][4];
#pragma unroll
  for (int r = 0; r < 2; ++r)
#pragma unroll
    for (int c = 0; c < 4; ++c) acc[r][c] = 0.f;

  const float* abase = attn + ((size_t)bh * S + i0) * S;
  const vf4*   vbase = (const vf4*)(v + (size_t)bh * S * D);

  for (int jt = 0; jt < 16; ++jt) {
    if (jt) __syncthreads();
    const int j0 = jt * 64;
#pragma unroll
    for (int it = 0; it < 2; ++it) {
      int fidx = t + it * 256;
      int row  = fidx >> 4;
      int c4   = fidx & 15;
      *(vf4*)&Ps[row][c4 * 4] =
          __builtin_nontemporal_load((const vf4*)(abase + (size_t)row * S + j0 + c4 * 4));
    }
#pragma unroll
    for (int it = 0; it < 4; ++it) {
      int fidx = t + it * 256;
      int row  = fidx >> 4;
      int c4   = fidx & 15;
      *(vf4*)&Vs[row][c4 * 4] = vbase[(size_t)(j0 + row) * 16 + c4];
    }
    __syncthreads();
#pragma unroll
    for (int jc = 0; jc < 16; ++jc) {
      float vr[4][4];
#pragma unroll
      for (int jj = 0; jj < 4; ++jj) {
        vf4 tv = *(const vf4*)&Vs[jc * 4 + jj][tx * 4];
        vr[jj][0] = tv.x; vr[jj][1] = tv.y; vr[jj][2] = tv.z; vr[jj][3] = tv.w;
      }
#pragma unroll
      for (int r = 0; r < 2; ++r) {
        vf4 pf = *(const vf4*)&Ps[ty + 16 * r][jc * 4];
        float pa[4] = {pf.x, pf.y, pf.z, pf.w};
#pragma unroll
        for (int c = 0; c < 4; ++c) {
#pragma unroll
          for (int jj = 0; jj < 4; ++jj) acc[r][c] += pa[jj] * vr[jj][c];
        }
      }
    }
  }

  float* obase = out + (size_t)bh * S * D;
#pragma unroll
  for (int r = 0; r < 2; ++r) {
    vf4 st = {acc[r][0], acc[r][1], acc[r][2], acc[r][3]};
    *(vf4*)(obase + (size_t)(i0 + ty + 16 * r) * D + tx * 4) = st;
  }
}

extern "C" void kernel_launch(void* const* d_in, const int* in_sizes, int n_in,
                              void* d_out, int out_size, void* d_ws, size_t ws_size,
                              hipStream_t stream) {
  const float* q    = (const float*)d_in[0];
  const float* k    = (const float*)d_in[1];
  const float* v    = (const float*)d_in[2];
  const int*   mask = (const int*)d_in[3];
  const float* rpr  = (const float*)d_in[4];

  float* out  = (float*)d_out;                    // (2,8,1024,64)
  float* attn = out + (size_t)2 * 8 * S * D;      // (2,8,1024,1024), also logits scratch

  hipLaunchKernelGGL(k_attn1,         dim3(8, 8, 16), dim3(256), 0, stream, q, k, attn);
  hipLaunchKernelGGL(k_attn2_softmax, dim3(1024, 2),  dim3(256), 0, stream, q, rpr, mask, attn);
  hipLaunchKernelGGL(k_pv,            dim3(32, 16),   dim3(256), 0, stream, attn, v, out);
}